// Round 4
// baseline (533.533 us; speedup 1.0000x reference)
//
#include <hip/hip_runtime.h>
#include <cstdint>

typedef unsigned short u16;
typedef __attribute__((ext_vector_type(8))) short short8;
typedef __attribute__((ext_vector_type(4))) float f32x4;
typedef __attribute__((ext_vector_type(4))) unsigned short u16x4;

// B=4 R=64 C=64 D=512 H=4 DH=128 S=4096, M = B*S = 16384

__device__ __forceinline__ u16 f2b(float f) {
  uint32_t x = __float_as_uint(f);
  x += 0x7fffu + ((x >> 16) & 1u);
  return (u16)(x >> 16);
}

// RNE f32x4 (scaled) -> 4 packed bf16
__device__ __forceinline__ uint2 pkbf16x4(f32x4 v, float s) {
  uint2 r;
  r.x = (uint32_t)f2b(v[0] * s) | ((uint32_t)f2b(v[1] * s) << 16);
  r.y = (uint32_t)f2b(v[2] * s) | ((uint32_t)f2b(v[3] * s) << 16);
  return r;
}

__device__ __forceinline__ void gload_lds16(const u16* g, u16* l) {
  __builtin_amdgcn_global_load_lds(
      (const __attribute__((address_space(1))) void*)g,
      (__attribute__((address_space(3))) void*)l, 16, 0, 0);
}

// ---------------- x fp32 -> bf16 cast ------------------------------------
__global__ __launch_bounds__(256) void xcast(const float* __restrict__ x,
                                             u16* __restrict__ xb) {
  const size_t i = (size_t)(blockIdx.x * 256 + threadIdx.x) * 8;
  const float4 a = *(const float4*)(x + i);
  const float4 b = *(const float4*)(x + i + 4);
  u16x4 lo = {f2b(a.x), f2b(a.y), f2b(a.z), f2b(a.w)};
  u16x4 hi = {f2b(b.x), f2b(b.y), f2b(b.z), f2b(b.w)};
  *(u16x4*)(xb + i) = lo;
  *(u16x4*)(xb + i + 4) = hi;
}

// ---------------- tiled weight transpose + bf16: wT[n][k] = w[k][n] ------
__global__ __launch_bounds__(256) void transpose_all(const float* __restrict__ wq,
                                                     const float* __restrict__ wk,
                                                     const float* __restrict__ wv,
                                                     const float* __restrict__ wo,
                                                     u16* __restrict__ wT,
                                                     u16* __restrict__ woT) {
  __shared__ __align__(16) u16 T[64][68];
  const int mtx = blockIdx.y;
  const float* src = (mtx == 0) ? wq : (mtx == 1) ? wk : (mtx == 2) ? wv : wo;
  u16* dst = (mtx < 3) ? (wT + (size_t)mtx * 262144) : woT;
  const int tr = blockIdx.x >> 3, tc = blockIdx.x & 7;
  const int tid = threadIdx.x;
#pragma unroll
  for (int p = 0; p < 4; ++p) {
    int i = p * 256 + tid;
    int row = i >> 4, c4 = i & 15;
    float4 v = *(const float4*)(src + (size_t)(tr * 64 + row) * 512 + tc * 64 + c4 * 4);
    T[c4 * 4 + 0][row] = f2b(v.x);
    T[c4 * 4 + 1][row] = f2b(v.y);
    T[c4 * 4 + 2][row] = f2b(v.z);
    T[c4 * 4 + 3][row] = f2b(v.w);
  }
  __syncthreads();
#pragma unroll
  for (int p = 0; p < 4; ++p) {
    int i = p * 256 + tid;
    int row = i >> 4, c4 = i & 15;
    *(u16x4*)(dst + (size_t)(tc * 64 + row) * 512 + tr * 64 + c4 * 4) =
        *(const u16x4*)&T[row][c4 * 4];
  }
}

// ---------------- QKV projection GEMM ------------------------------------
// 512 threads, M=128 (s), N=256 (dh within one of q/k/v).
// For q/k: A=W, B=x -> C row=dh, col=s -> lane holds 4 consecutive dh at
// fixed s -> vectorized 8B stores into qbuf/kbuf [s][dh].
// For v:   A=x, B=W -> C row=s, col=dh -> 4 consecutive s at fixed dh ->
// vectorized stores into vtbuf [dh][s].
__global__ __launch_bounds__(512, 4) void qkv_gemm(const u16* __restrict__ xb,
                                                   const u16* __restrict__ wT_all,
                                                   u16* __restrict__ qbuf,
                                                   u16* __restrict__ kbuf,
                                                   u16* __restrict__ vtbuf) {
  __shared__ __align__(16) u16 As[128][64];   // x rows (s), unpadded for lds-DMA
  __shared__ __align__(16) u16 Bs[256][64];   // wT rows (dh)
  const int tid = threadIdx.x;
  const int wave = tid >> 6, lane = tid & 63, quad = lane >> 4, l16 = lane & 15;
  const int wm = wave >> 2, wn = wave & 3;
  const int m0 = blockIdx.x * 128;
  const int which = blockIdx.y >> 1;            // 0=q 1=k 2=v
  const int n0 = (blockIdx.y & 1) * 256;        // dh offset within which
  const u16* wTb = wT_all + (size_t)which * 262144 + (size_t)n0 * 512;

  f32x4 acc[4][4];
  const f32x4 fz = {0.f, 0.f, 0.f, 0.f};
#pragma unroll
  for (int i = 0; i < 4; ++i)
#pragma unroll
    for (int j = 0; j < 4; ++j) acc[i][j] = fz;

  const int lrow = lane >> 3, lcol = (lane & 7) * 8;

  for (int k0 = 0; k0 < 512; k0 += 64) {
    // async global->LDS staging, 1024 B per wave-op
#pragma unroll
    for (int p = 0; p < 2; ++p) {
      const int row = (wave * 2 + p) * 8 + lrow;
      gload_lds16(xb + (size_t)(m0 + row) * 512 + k0 + lcol,
                  &As[0][0] + (wave * 2 + p) * 512 + lane * 8);
    }
#pragma unroll
    for (int p = 0; p < 4; ++p) {
      const int row = (wave * 4 + p) * 8 + lrow;
      gload_lds16(wTb + (size_t)row * 512 + k0 + lcol,
                  &Bs[0][0] + (wave * 4 + p) * 512 + lane * 8);
    }
    __syncthreads();
#pragma unroll
    for (int ks = 0; ks < 2; ++ks) {
      short8 xf[4], wf[4];
#pragma unroll
      for (int mt = 0; mt < 4; ++mt)
        xf[mt] = *(const short8*)&As[wm * 64 + mt * 16 + l16][ks * 32 + quad * 8];
#pragma unroll
      for (int nt = 0; nt < 4; ++nt)
        wf[nt] = *(const short8*)&Bs[wn * 64 + nt * 16 + l16][ks * 32 + quad * 8];
      if (which < 2) {
#pragma unroll
        for (int mt = 0; mt < 4; ++mt)
#pragma unroll
          for (int nt = 0; nt < 4; ++nt)
            acc[mt][nt] = __builtin_amdgcn_mfma_f32_16x16x32_bf16(wf[nt], xf[mt],
                                                                  acc[mt][nt], 0, 0, 0);
      } else {
#pragma unroll
        for (int mt = 0; mt < 4; ++mt)
#pragma unroll
          for (int nt = 0; nt < 4; ++nt)
            acc[mt][nt] = __builtin_amdgcn_mfma_f32_16x16x32_bf16(xf[mt], wf[nt],
                                                                  acc[mt][nt], 0, 0, 0);
      }
    }
    __syncthreads();
  }

  if (which < 2) {
    const float scl = (which == 0) ? 0.08838834764831845f : 1.0f;  // DH^-0.5 on q
    u16* dst = (which == 0) ? qbuf : kbuf;
#pragma unroll
    for (int mt = 0; mt < 4; ++mt) {
      const int s = m0 + wm * 64 + mt * 16 + l16;
      const int b = s >> 12, sl = s & 4095;
#pragma unroll
      for (int nt = 0; nt < 4; ++nt) {
        const int dhg = n0 + wn * 64 + nt * 16 + quad * 4;
        const int h = dhg >> 7, dhh = dhg & 127;
        const int bh = b * 4 + h;
        uint2 pk = pkbf16x4(acc[mt][nt], scl);
        *(uint2*)(dst + ((size_t)(bh * 4096 + sl)) * 128 + dhh) = pk;
      }
    }
  } else {
#pragma unroll
    for (int mt = 0; mt < 4; ++mt) {
      const int s0q = m0 + wm * 64 + mt * 16 + quad * 4;
      const int b = s0q >> 12, sl = s0q & 4095;
#pragma unroll
      for (int nt = 0; nt < 4; ++nt) {
        const int dhg = n0 + wn * 64 + nt * 16 + l16;
        const int h = dhg >> 7, dhh = dhg & 127;
        const int bh = b * 4 + h;
        uint2 pk = pkbf16x4(acc[mt][nt], 1.0f);
        *(uint2*)(vtbuf + ((size_t)(bh * 128 + dhh)) * 4096 + sl) = pk;
      }
    }
  }
}

// ---------------- causal flash attention with factorized rel bias --------
// 512 threads, 128 queries/block. Register-prefetch pipeline: K/V for tile
// kt+1 are loaded into VGPRs during tile kt's compute, hiding L2/L3 latency.
__global__ __launch_bounds__(512, 4) void attn(const u16* __restrict__ qbuf,
                                               const u16* __restrict__ kbuf,
                                               const u16* __restrict__ vtbuf,
                                               const float* __restrict__ rel_row,
                                               const float* __restrict__ rel_col,
                                               u16* __restrict__ obuf) {
  __shared__ __align__(16) u16 Ks[64][136];     // [key][dh], 68 dw = 4 mod 32
  __shared__ __align__(16) u16 Vt[128][72];     // [dh][key], 36 dw = 4 mod 32
  __shared__ __align__(16) u16 Plds[8][16][72]; // per-wave [q][key]
  __shared__ float rcol[128];
  __shared__ float rrow[128];

  const int tid = threadIdx.x;
  const int wave = tid >> 6, lane = tid & 63, quad = lane >> 4, l16 = lane & 15;
  const int bh = blockIdx.x & 15;
  // balanced pairing: block c (heavy) shares a CU with block c+256 (light)
  const int qt = (blockIdx.x < 256) ? (31 - (blockIdx.x >> 4))
                                    : ((blockIdx.x >> 4) - 16);
  const int b = bh >> 2, h = bh & 3;

  if (tid < 128) rcol[tid] = rel_col[h * 128 + tid];
  else if (tid < 256) rrow[tid - 128] = rel_row[h * 128 + (tid - 128)];

  const int q_loc = wave * 16 + l16;
  const int q_glob = qt * 128 + q_loc;
  const int qr = 2 * qt + (wave >> 2);
  const int qc = q_glob & 63;

  const u16* qrow = qbuf + ((size_t)bh * 4096 + q_glob) * 128;
  short8 qf[4];
#pragma unroll
  for (int ks = 0; ks < 4; ++ks) qf[ks] = *(const short8*)(qrow + ks * 32 + quad * 8);

  __syncthreads();   // rcol/rrow visible

  const float LOG2E = 1.4426950408889634f;
  float rc2[4][4];
#pragma unroll
  for (int nt = 0; nt < 4; ++nt)
#pragma unroll
    for (int r = 0; r < 4; ++r)
      rc2[nt][r] = rcol[63 + nt * 16 + quad * 4 + r - qc] * LOG2E;

  const f32x4 fz = {0.f, 0.f, 0.f, 0.f};
  f32x4 oacc[8];
#pragma unroll
  for (int i = 0; i < 8; ++i) oacc[i] = fz;
  float l_run = 0.0f;

  const u16* kbase = kbuf + (size_t)bh * 4096 * 128;
  const u16* vbase = vtbuf + (size_t)bh * 128 * 4096;
  const int kr = tid >> 4, kc = (tid & 15) * 8;      // K-tile staging coords
  const int vr = tid >> 3, vc = (tid & 7) * 8;       // V-tile staging coords

  uint4 kreg0, kreg1, vreg0, vreg1;
  {
    const u16* ksrc = kbase;
    const u16* vsrc = vbase;
    kreg0 = *(const uint4*)(ksrc + kr * 128 + kc);
    kreg1 = *(const uint4*)(ksrc + (32 + kr) * 128 + kc);
    vreg0 = *(const uint4*)(vsrc + (size_t)vr * 4096 + vc);
    vreg1 = *(const uint4*)(vsrc + (size_t)(64 + vr) * 4096 + vc);
  }

  const int ktmax = 2 * qt + 1;
  for (int kt = 0; kt <= ktmax; ++kt) {
    __syncthreads();   // all waves done computing on previous LDS tiles
    *(uint4*)&Ks[kr][kc] = kreg0;
    *(uint4*)&Ks[32 + kr][kc] = kreg1;
    *(uint4*)&Vt[vr][vc] = vreg0;
    *(uint4*)&Vt[64 + vr][vc] = vreg1;
    __syncthreads();
    if (kt < ktmax) {   // prefetch next tile; latency hides under compute
      const u16* ksrc = kbase + (kt + 1) * 64 * 128;
      const u16* vsrc = vbase + (kt + 1) * 64;
      kreg0 = *(const uint4*)(ksrc + kr * 128 + kc);
      kreg1 = *(const uint4*)(ksrc + (32 + kr) * 128 + kc);
      vreg0 = *(const uint4*)(vsrc + (size_t)vr * 4096 + vc);
      vreg1 = *(const uint4*)(vsrc + (size_t)(64 + vr) * 4096 + vc);
    }

    if (kt <= qr) {
      // Sᵀ tiles: rows = key (nt), cols = q (l16)
      f32x4 sacc[4];
#pragma unroll
      for (int nt = 0; nt < 4; ++nt) sacc[nt] = fz;
#pragma unroll
      for (int ks = 0; ks < 4; ++ks)
#pragma unroll
        for (int nt = 0; nt < 4; ++nt) {
          short8 kf = *(const short8*)&Ks[nt * 16 + l16][ks * 32 + quad * 8];
          sacc[nt] = __builtin_amdgcn_mfma_f32_16x16x32_bf16(kf, qf[ks], sacc[nt], 0, 0, 0);
        }

      const float browl = rrow[63 + kt - qr] * LOG2E;
      const bool diag = (kt == qr);
#pragma unroll
      for (int nt = 0; nt < 4; ++nt) {
        f32x4 pv;
#pragma unroll
        for (int r = 0; r < 4; ++r) {
          const int kc2 = nt * 16 + quad * 4 + r;
          float p = exp2f(fmaf(sacc[nt][r], LOG2E, rc2[nt][r] + browl));
          if (diag && kc2 > qc) p = 0.0f;
          l_run += p;
          pv[r] = p;
        }
        *(uint2*)&Plds[wave][l16][nt * 16 + quad * 4] = pkbf16x4(pv, 1.0f);
      }

      // Oᵀ += Vᵀ·Pᵀ  (rows = dh, cols = q)
#pragma unroll
      for (int ks2 = 0; ks2 < 2; ++ks2) {
        short8 pf = *(const short8*)&Plds[wave][l16][ks2 * 32 + quad * 8];
#pragma unroll
        for (int mt = 0; mt < 8; ++mt) {
          short8 vf = *(const short8*)&Vt[mt * 16 + l16][ks2 * 32 + quad * 8];
          oacc[mt] = __builtin_amdgcn_mfma_f32_16x16x32_bf16(vf, pf, oacc[mt], 0, 0, 0);
        }
      }
    }
  }

  l_run += __shfl_xor(l_run, 16);
  l_run += __shfl_xor(l_run, 32);
  const float inv_l = 1.0f / l_run;
  u16* orow = obuf + ((size_t)b * 4096 + q_glob) * 512 + h * 128;
#pragma unroll
  for (int mt = 0; mt < 8; ++mt)
    *(uint2*)(orow + mt * 16 + quad * 4) = pkbf16x4(oacc[mt], inv_l);
}

// ---------------- output projection GEMM ---------------------------------
// A=wo, B=obuf -> C row=d, col=s -> lane holds 4 consecutive d at fixed s
// -> float4 stores.
__global__ __launch_bounds__(512, 4) void out_gemm(const u16* __restrict__ obuf,
                                                   const u16* __restrict__ woT,
                                                   float* __restrict__ out) {
  __shared__ __align__(16) u16 As[128][64];   // obuf rows (s)
  __shared__ __align__(16) u16 Bs[256][64];   // woT rows (d)
  const int tid = threadIdx.x;
  const int wave = tid >> 6, lane = tid & 63, quad = lane >> 4, l16 = lane & 15;
  const int wm = wave >> 2, wn = wave & 3;
  const int m0 = blockIdx.x * 128;
  const int n0 = blockIdx.y * 256;

  f32x4 acc[4][4];
  const f32x4 fz = {0.f, 0.f, 0.f, 0.f};
#pragma unroll
  for (int i = 0; i < 4; ++i)
#pragma unroll
    for (int j = 0; j < 4; ++j) acc[i][j] = fz;

  const int lrow = lane >> 3, lcol = (lane & 7) * 8;

  for (int k0 = 0; k0 < 512; k0 += 64) {
#pragma unroll
    for (int p = 0; p < 2; ++p) {
      const int row = (wave * 2 + p) * 8 + lrow;
      gload_lds16(obuf + (size_t)(m0 + row) * 512 + k0 + lcol,
                  &As[0][0] + (wave * 2 + p) * 512 + lane * 8);
    }
#pragma unroll
    for (int p = 0; p < 4; ++p) {
      const int row = (wave * 4 + p) * 8 + lrow;
      gload_lds16(woT + (size_t)(n0 + row) * 512 + k0 + lcol,
                  &Bs[0][0] + (wave * 4 + p) * 512 + lane * 8);
    }
    __syncthreads();
#pragma unroll
    for (int ks = 0; ks < 2; ++ks) {
      short8 of[4], wf[4];
#pragma unroll
      for (int mt = 0; mt < 4; ++mt)
        of[mt] = *(const short8*)&As[wm * 64 + mt * 16 + l16][ks * 32 + quad * 8];
#pragma unroll
      for (int nt = 0; nt < 4; ++nt)
        wf[nt] = *(const short8*)&Bs[wn * 64 + nt * 16 + l16][ks * 32 + quad * 8];
#pragma unroll
      for (int mt = 0; mt < 4; ++mt)
#pragma unroll
        for (int nt = 0; nt < 4; ++nt)
          acc[mt][nt] = __builtin_amdgcn_mfma_f32_16x16x32_bf16(wf[nt], of[mt],
                                                                acc[mt][nt], 0, 0, 0);
    }
    __syncthreads();
  }

#pragma unroll
  for (int mt = 0; mt < 4; ++mt) {
    const int s = m0 + wm * 64 + mt * 16 + l16;
#pragma unroll
    for (int nt = 0; nt < 4; ++nt) {
      const int d0 = n0 + wn * 64 + nt * 16 + quad * 4;
      float4 st = {acc[mt][nt][0], acc[mt][nt][1], acc[mt][nt][2], acc[mt][nt][3]};
      *(float4*)(out + (size_t)s * 512 + d0) = st;
    }
  }
}

// ---------------- launch --------------------------------------------------
extern "C" void kernel_launch(void* const* d_in, const int* in_sizes, int n_in,
                              void* d_out, int out_size, void* d_ws, size_t ws_size,
                              hipStream_t stream) {
  const float* x       = (const float*)d_in[0];
  const float* wq      = (const float*)d_in[1];
  const float* wk      = (const float*)d_in[2];
  const float* wv      = (const float*)d_in[3];
  const float* wo      = (const float*)d_in[4];
  const float* rel_row = (const float*)d_in[5];
  const float* rel_col = (const float*)d_in[6];
  float* out = (float*)d_out;

  char* ws = (char*)d_ws;
  u16* wT    = (u16*)(ws);                               // 3 * 512*512 bf16
  u16* woT   = (u16*)(ws + 1572864);                     // 512*512 bf16
  u16* qbuf  = (u16*)(ws + 2097152);                     // 16 MiB
  u16* kbuf  = (u16*)(ws + 2097152 + 16777216);          // 16 MiB
  u16* vtbuf = (u16*)(ws + 2097152 + 2 * 16777216);      // 16 MiB
  u16* obuf  = (u16*)(ws + 2097152 + 3 * 16777216);      // 16 MiB
  u16* xb    = obuf;  // xb consumed by qkv_gemm before attn writes obuf

  xcast<<<4096, 256, 0, stream>>>(x, xb);
  transpose_all<<<dim3(64, 4), 256, 0, stream>>>(wq, wk, wv, wo, wT, woT);
  qkv_gemm<<<dim3(128, 6), 512, 0, stream>>>(xb, wT, qbuf, kbuf, vtbuf);
  attn<<<512, 512, 0, stream>>>(qbuf, kbuf, vtbuf, rel_row, rel_col, obuf);
  out_gemm<<<dim3(128, 2), 512, 0, stream>>>(obuf, woT, out);
}

// Round 5
// 313.788 us; speedup vs baseline: 1.7003x; 1.7003x over previous
//
#include <hip/hip_runtime.h>
#include <cstdint>

typedef unsigned short u16;
typedef __attribute__((ext_vector_type(8))) short short8;
typedef __attribute__((ext_vector_type(4))) float f32x4;
typedef __attribute__((ext_vector_type(4))) unsigned short u16x4;

// B=4 R=64 C=64 D=512 H=4 DH=128 S=4096, M = B*S = 16384

__device__ __forceinline__ u16 f2b(float f) {
  uint32_t x = __float_as_uint(f);
  x += 0x7fffu + ((x >> 16) & 1u);
  return (u16)(x >> 16);
}

// RNE f32x4 (scaled) -> 4 packed bf16
__device__ __forceinline__ uint2 pkbf16x4(f32x4 v, float s) {
  uint2 r;
  r.x = (uint32_t)f2b(v[0] * s) | ((uint32_t)f2b(v[1] * s) << 16);
  r.y = (uint32_t)f2b(v[2] * s) | ((uint32_t)f2b(v[3] * s) << 16);
  return r;
}

#define LDS_FENCE() asm volatile("s_waitcnt lgkmcnt(0)" ::: "memory")

// ---------------- x fp32 -> bf16 cast ------------------------------------
__global__ __launch_bounds__(256) void xcast(const float* __restrict__ x,
                                             u16* __restrict__ xb) {
  const size_t i = (size_t)(blockIdx.x * 256 + threadIdx.x) * 8;
  const float4 a = *(const float4*)(x + i);
  const float4 b = *(const float4*)(x + i + 4);
  u16x4 lo = {f2b(a.x), f2b(a.y), f2b(a.z), f2b(a.w)};
  u16x4 hi = {f2b(b.x), f2b(b.y), f2b(b.z), f2b(b.w)};
  *(u16x4*)(xb + i) = lo;
  *(u16x4*)(xb + i + 4) = hi;
}

// ---------------- tiled weight transpose + bf16: wT[n][k] = w[k][n] ------
__global__ __launch_bounds__(256) void transpose_all(const float* __restrict__ wq,
                                                     const float* __restrict__ wk,
                                                     const float* __restrict__ wv,
                                                     const float* __restrict__ wo,
                                                     u16* __restrict__ wT,
                                                     u16* __restrict__ woT) {
  __shared__ __align__(16) u16 T[64][68];
  const int mtx = blockIdx.y;
  const float* src = (mtx == 0) ? wq : (mtx == 1) ? wk : (mtx == 2) ? wv : wo;
  u16* dst = (mtx < 3) ? (wT + (size_t)mtx * 262144) : woT;
  const int tr = blockIdx.x >> 3, tc = blockIdx.x & 7;
  const int tid = threadIdx.x;
#pragma unroll
  for (int p = 0; p < 4; ++p) {
    int i = p * 256 + tid;
    int row = i >> 4, c4 = i & 15;
    float4 v = *(const float4*)(src + (size_t)(tr * 64 + row) * 512 + tc * 64 + c4 * 4);
    T[c4 * 4 + 0][row] = f2b(v.x);
    T[c4 * 4 + 1][row] = f2b(v.y);
    T[c4 * 4 + 2][row] = f2b(v.z);
    T[c4 * 4 + 3][row] = f2b(v.w);
  }
  __syncthreads();
#pragma unroll
  for (int p = 0; p < 4; ++p) {
    int i = p * 256 + tid;
    int row = i >> 4, c4 = i & 15;
    *(u16x4*)(dst + (size_t)(tc * 64 + row) * 512 + tr * 64 + c4 * 4) =
        *(const u16x4*)&T[row][c4 * 4];
  }
}

// ---------------- QKV projection GEMM ------------------------------------
// 512 threads, M=128 (s), N=256 (dh slice of one of q/k/v).
// q/k: mfma(W, x): C row=dh, col=s.  v: mfma(x, W): C row=s, col=dh.
// Epilogue: per-wave LDS bounce -> fully coalesced 16B-lane stores.
__global__ __launch_bounds__(512, 2) void qkv_gemm(const u16* __restrict__ xb,
                                                   const u16* __restrict__ wT_all,
                                                   u16* __restrict__ qbuf,
                                                   u16* __restrict__ kbuf,
                                                   u16* __restrict__ vtbuf) {
  __shared__ __align__(16) u16 smem[128 * 72 + 256 * 72];  // As | Bs, 54 KB
  u16* As = smem;              // [128][72]
  u16* Bs = smem + 128 * 72;   // [256][72]
  const int tid = threadIdx.x;
  const int wave = tid >> 6, lane = tid & 63, quad = lane >> 4, l16 = lane & 15;
  const int wm = wave >> 2, wn = wave & 3;
  const int m0 = blockIdx.x * 128;
  const int which = blockIdx.y >> 1;            // 0=q 1=k 2=v
  const int n0 = (blockIdx.y & 1) * 256;        // dh offset within which
  const u16* wTb = wT_all + (size_t)which * 262144 + (size_t)n0 * 512;

  f32x4 acc[4][4];
  const f32x4 fz = {0.f, 0.f, 0.f, 0.f};
#pragma unroll
  for (int i = 0; i < 4; ++i)
#pragma unroll
    for (int j = 0; j < 4; ++j) acc[i][j] = fz;

  for (int k0 = 0; k0 < 512; k0 += 64) {
#pragma unroll
    for (int p = 0; p < 2; ++p) {
      int i = p * 512 + tid, row = i >> 3, c8 = i & 7;
      uint4 v = *(const uint4*)(xb + (size_t)(m0 + row) * 512 + k0 + c8 * 8);
      *(uint4*)&As[row * 72 + c8 * 8] = v;
    }
#pragma unroll
    for (int p = 0; p < 4; ++p) {
      int i = p * 512 + tid, row = i >> 3, c8 = i & 7;
      uint4 v = *(const uint4*)(wTb + (size_t)row * 512 + k0 + c8 * 8);
      *(uint4*)&Bs[row * 72 + c8 * 8] = v;
    }
    __syncthreads();
#pragma unroll
    for (int ks = 0; ks < 2; ++ks) {
      short8 xf[4], wf[4];
#pragma unroll
      for (int mt = 0; mt < 4; ++mt)
        xf[mt] = *(const short8*)&As[(wm * 64 + mt * 16 + l16) * 72 + ks * 32 + quad * 8];
#pragma unroll
      for (int nt = 0; nt < 4; ++nt)
        wf[nt] = *(const short8*)&Bs[(wn * 64 + nt * 16 + l16) * 72 + ks * 32 + quad * 8];
      if (which < 2) {
#pragma unroll
        for (int mt = 0; mt < 4; ++mt)
#pragma unroll
          for (int nt = 0; nt < 4; ++nt)
            acc[mt][nt] = __builtin_amdgcn_mfma_f32_16x16x32_bf16(wf[nt], xf[mt],
                                                                  acc[mt][nt], 0, 0, 0);
      } else {
#pragma unroll
        for (int mt = 0; mt < 4; ++mt)
#pragma unroll
          for (int nt = 0; nt < 4; ++nt)
            acc[mt][nt] = __builtin_amdgcn_mfma_f32_16x16x32_bf16(xf[mt], wf[nt],
                                                                  acc[mt][nt], 0, 0, 0);
      }
    }
    __syncthreads();
  }
  // After the final barrier each wave owns a private smem slice (3072 u16).
  u16* sw = smem + wave * 3072;
  const int dhg0 = n0 + wn * 64;
  const int h = dhg0 >> 7, dhh0 = dhg0 & 127;
  const int bq = m0 >> 12;
  const int bh = bq * 4 + h;
  const int sl0 = (m0 & 4095) + wm * 64;

  if (which < 2) {
    const float scl = (which == 0) ? 0.08838834764831845f : 1.0f;  // DH^-0.5 on q
    u16* dst = (which == 0) ? qbuf : kbuf;
#pragma unroll
    for (int mt = 0; mt < 4; ++mt) {
      LDS_FENCE();  // prior readback done before overwrite
#pragma unroll
      for (int nt = 0; nt < 4; ++nt)
        *(uint2*)&sw[l16 * 68 + nt * 16 + quad * 4] = pkbf16x4(acc[mt][nt], scl);
      LDS_FENCE();
#pragma unroll
      for (int p = 0; p < 2; ++p) {
        const int sr = p * 8 + (lane >> 3), dl = (lane & 7) * 8;
        uint4 v = *(const uint4*)&sw[sr * 68 + dl];
        const int sl = sl0 + mt * 16 + sr;
        *(uint4*)(dst + ((size_t)(bh * 4096 + sl)) * 128 + dhh0 + dl) = v;
      }
    }
  } else {
    // v: scratch [64 dh][32 s + pad4], two mt-pairs
#pragma unroll
    for (int p2 = 0; p2 < 2; ++p2) {
      LDS_FENCE();
#pragma unroll
      for (int m2 = 0; m2 < 2; ++m2) {
        const int mt = p2 * 2 + m2;
#pragma unroll
        for (int nt = 0; nt < 4; ++nt)
          *(uint2*)&sw[(nt * 16 + l16) * 36 + m2 * 16 + quad * 4] =
              pkbf16x4(acc[mt][nt], 1.0f);
      }
      LDS_FENCE();
#pragma unroll
      for (int j = 0; j < 4; ++j) {
        const int dl = j * 16 + (lane >> 2), so = (lane & 3) * 8;
        uint4 v = *(const uint4*)&sw[dl * 36 + so];
        const int sl = sl0 + p2 * 32 + so;
        *(uint4*)(vtbuf + ((size_t)(bh * 128 + dhh0 + dl)) * 4096 + sl) = v;
      }
    }
  }
}

// ---------------- causal flash attention with factorized rel bias --------
// 512 threads, 128 queries/block. Register-prefetch pipeline: K/V for tile
// kt+1 are loaded into VGPRs during tile kt's compute, hiding L2/L3 latency.
__global__ __launch_bounds__(512, 4) void attn(const u16* __restrict__ qbuf,
                                               const u16* __restrict__ kbuf,
                                               const u16* __restrict__ vtbuf,
                                               const float* __restrict__ rel_row,
                                               const float* __restrict__ rel_col,
                                               u16* __restrict__ obuf) {
  __shared__ __align__(16) u16 Ks[64][136];     // [key][dh], 68 dw = 4 mod 32
  __shared__ __align__(16) u16 Vt[128][72];     // [dh][key], 36 dw = 4 mod 32
  __shared__ __align__(16) u16 Plds[8][16][72]; // per-wave [q][key]
  __shared__ float rcol[128];
  __shared__ float rrow[128];

  const int tid = threadIdx.x;
  const int wave = tid >> 6, lane = tid & 63, quad = lane >> 4, l16 = lane & 15;
  const int bh = blockIdx.x & 15;
  // balanced pairing: block c (heavy) shares a CU with block c+256 (light)
  const int qt = (blockIdx.x < 256) ? (31 - (blockIdx.x >> 4))
                                    : ((blockIdx.x >> 4) - 16);
  const int b = bh >> 2, h = bh & 3;

  if (tid < 128) rcol[tid] = rel_col[h * 128 + tid];
  else if (tid < 256) rrow[tid - 128] = rel_row[h * 128 + (tid - 128)];

  const int q_loc = wave * 16 + l16;
  const int q_glob = qt * 128 + q_loc;
  const int qr = 2 * qt + (wave >> 2);
  const int qc = q_glob & 63;

  const u16* qrow = qbuf + ((size_t)bh * 4096 + q_glob) * 128;
  short8 qf[4];
#pragma unroll
  for (int ks = 0; ks < 4; ++ks) qf[ks] = *(const short8*)(qrow + ks * 32 + quad * 8);

  __syncthreads();   // rcol/rrow visible

  const float LOG2E = 1.4426950408889634f;
  float rc2[4][4];
#pragma unroll
  for (int nt = 0; nt < 4; ++nt)
#pragma unroll
    for (int r = 0; r < 4; ++r)
      rc2[nt][r] = rcol[63 + nt * 16 + quad * 4 + r - qc] * LOG2E;

  const f32x4 fz = {0.f, 0.f, 0.f, 0.f};
  f32x4 oacc[8];
#pragma unroll
  for (int i = 0; i < 8; ++i) oacc[i] = fz;
  float l_run = 0.0f;

  const u16* kbase = kbuf + (size_t)bh * 4096 * 128;
  const u16* vbase = vtbuf + (size_t)bh * 128 * 4096;
  const int kr = tid >> 4, kc = (tid & 15) * 8;      // K-tile staging coords
  const int vr = tid >> 3, vc = (tid & 7) * 8;       // V-tile staging coords

  uint4 kreg0, kreg1, vreg0, vreg1;
  {
    const u16* ksrc = kbase;
    const u16* vsrc = vbase;
    kreg0 = *(const uint4*)(ksrc + kr * 128 + kc);
    kreg1 = *(const uint4*)(ksrc + (32 + kr) * 128 + kc);
    vreg0 = *(const uint4*)(vsrc + (size_t)vr * 4096 + vc);
    vreg1 = *(const uint4*)(vsrc + (size_t)(64 + vr) * 4096 + vc);
  }

  const int ktmax = 2 * qt + 1;
  for (int kt = 0; kt <= ktmax; ++kt) {
    __syncthreads();   // all waves done computing on previous LDS tiles
    *(uint4*)&Ks[kr][kc] = kreg0;
    *(uint4*)&Ks[32 + kr][kc] = kreg1;
    *(uint4*)&Vt[vr][vc] = vreg0;
    *(uint4*)&Vt[64 + vr][vc] = vreg1;
    __syncthreads();
    if (kt < ktmax) {   // prefetch next tile; latency hides under compute
      const u16* ksrc = kbase + (kt + 1) * 64 * 128;
      const u16* vsrc = vbase + (kt + 1) * 64;
      kreg0 = *(const uint4*)(ksrc + kr * 128 + kc);
      kreg1 = *(const uint4*)(ksrc + (32 + kr) * 128 + kc);
      vreg0 = *(const uint4*)(vsrc + (size_t)vr * 4096 + vc);
      vreg1 = *(const uint4*)(vsrc + (size_t)(64 + vr) * 4096 + vc);
    }

    if (kt <= qr) {
      // Sᵀ tiles: rows = key (nt), cols = q (l16)
      f32x4 sacc[4];
#pragma unroll
      for (int nt = 0; nt < 4; ++nt) sacc[nt] = fz;
#pragma unroll
      for (int ks = 0; ks < 4; ++ks)
#pragma unroll
        for (int nt = 0; nt < 4; ++nt) {
          short8 kf = *(const short8*)&Ks[nt * 16 + l16][ks * 32 + quad * 8];
          sacc[nt] = __builtin_amdgcn_mfma_f32_16x16x32_bf16(kf, qf[ks], sacc[nt], 0, 0, 0);
        }

      const float browl = rrow[63 + kt - qr] * LOG2E;
      const bool diag = (kt == qr);
#pragma unroll
      for (int nt = 0; nt < 4; ++nt) {
        f32x4 pv;
#pragma unroll
        for (int r = 0; r < 4; ++r) {
          const int kc2 = nt * 16 + quad * 4 + r;
          float p = exp2f(fmaf(sacc[nt][r], LOG2E, rc2[nt][r] + browl));
          if (diag && kc2 > qc) p = 0.0f;
          l_run += p;
          pv[r] = p;
        }
        *(uint2*)&Plds[wave][l16][nt * 16 + quad * 4] = pkbf16x4(pv, 1.0f);
      }

      // Oᵀ += Vᵀ·Pᵀ  (rows = dh, cols = q)
#pragma unroll
      for (int ks2 = 0; ks2 < 2; ++ks2) {
        short8 pf = *(const short8*)&Plds[wave][l16][ks2 * 32 + quad * 8];
#pragma unroll
        for (int mt = 0; mt < 8; ++mt) {
          short8 vf = *(const short8*)&Vt[mt * 16 + l16][ks2 * 32 + quad * 8];
          oacc[mt] = __builtin_amdgcn_mfma_f32_16x16x32_bf16(vf, pf, oacc[mt], 0, 0, 0);
        }
      }
    }
  }

  l_run += __shfl_xor(l_run, 16);
  l_run += __shfl_xor(l_run, 32);
  const float inv_l = 1.0f / l_run;
  u16* orow = obuf + ((size_t)b * 4096 + q_glob) * 512 + h * 128;
#pragma unroll
  for (int mt = 0; mt < 8; ++mt)
    *(uint2*)(orow + mt * 16 + quad * 4) = pkbf16x4(oacc[mt], inv_l);
}

// ---------------- output projection GEMM ---------------------------------
// mfma(wo, obuf): C row=d, col=s. Per-wave LDS-bounce epilogue -> 256 B runs.
__global__ __launch_bounds__(512, 2) void out_gemm(const u16* __restrict__ obuf,
                                                   const u16* __restrict__ woT,
                                                   float* __restrict__ out) {
  __shared__ __align__(16) u16 smem[128 * 72 + 256 * 72];
  u16* As = smem;              // [128][72] obuf rows (s)
  u16* Bs = smem + 128 * 72;   // [256][72] woT rows (d)
  const int tid = threadIdx.x;
  const int wave = tid >> 6, lane = tid & 63, quad = lane >> 4, l16 = lane & 15;
  const int wm = wave >> 2, wn = wave & 3;
  const int m0 = blockIdx.x * 128;
  const int n0 = blockIdx.y * 256;

  f32x4 acc[4][4];
  const f32x4 fz = {0.f, 0.f, 0.f, 0.f};
#pragma unroll
  for (int i = 0; i < 4; ++i)
#pragma unroll
    for (int j = 0; j < 4; ++j) acc[i][j] = fz;

  for (int k0 = 0; k0 < 512; k0 += 64) {
#pragma unroll
    for (int p = 0; p < 2; ++p) {
      int i = p * 512 + tid, row = i >> 3, c8 = i & 7;
      uint4 v = *(const uint4*)(obuf + (size_t)(m0 + row) * 512 + k0 + c8 * 8);
      *(uint4*)&As[row * 72 + c8 * 8] = v;
    }
#pragma unroll
    for (int p = 0; p < 4; ++p) {
      int i = p * 512 + tid, row = i >> 3, c8 = i & 7;
      uint4 v = *(const uint4*)(woT + (size_t)(n0 + row) * 512 + k0 + c8 * 8);
      *(uint4*)&Bs[row * 72 + c8 * 8] = v;
    }
    __syncthreads();
#pragma unroll
    for (int ks = 0; ks < 2; ++ks) {
      short8 of[4], wf[4];
#pragma unroll
      for (int mt = 0; mt < 4; ++mt)
        of[mt] = *(const short8*)&As[(wm * 64 + mt * 16 + l16) * 72 + ks * 32 + quad * 8];
#pragma unroll
      for (int nt = 0; nt < 4; ++nt)
        wf[nt] = *(const short8*)&Bs[(wn * 64 + nt * 16 + l16) * 72 + ks * 32 + quad * 8];
#pragma unroll
      for (int mt = 0; mt < 4; ++mt)
#pragma unroll
        for (int nt = 0; nt < 4; ++nt)
          acc[mt][nt] = __builtin_amdgcn_mfma_f32_16x16x32_bf16(wf[nt], of[mt],
                                                                acc[mt][nt], 0, 0, 0);
    }
    __syncthreads();
  }

  float* swf = (float*)smem + wave * 1536;   // per-wave [16 s][68 d] f32
#pragma unroll
  for (int mt = 0; mt < 4; ++mt) {
    LDS_FENCE();
#pragma unroll
    for (int nt = 0; nt < 4; ++nt)
      *(f32x4*)&swf[l16 * 68 + nt * 16 + quad * 4] = acc[mt][nt];
    LDS_FENCE();
#pragma unroll
    for (int p = 0; p < 4; ++p) {
      const int sr = p * 4 + (lane >> 4), dl = l16 * 4;
      float4 v = *(const float4*)&swf[sr * 68 + dl];
      const int s = m0 + wm * 64 + mt * 16 + sr;
      *(float4*)(out + (size_t)s * 512 + n0 + wn * 64 + dl) = v;
    }
  }
}

// ---------------- launch --------------------------------------------------
extern "C" void kernel_launch(void* const* d_in, const int* in_sizes, int n_in,
                              void* d_out, int out_size, void* d_ws, size_t ws_size,
                              hipStream_t stream) {
  const float* x       = (const float*)d_in[0];
  const float* wq      = (const float*)d_in[1];
  const float* wk      = (const float*)d_in[2];
  const float* wv      = (const float*)d_in[3];
  const float* wo      = (const float*)d_in[4];
  const float* rel_row = (const float*)d_in[5];
  const float* rel_col = (const float*)d_in[6];
  float* out = (float*)d_out;

  char* ws = (char*)d_ws;
  u16* wT    = (u16*)(ws);                               // 3 * 512*512 bf16
  u16* woT   = (u16*)(ws + 1572864);                     // 512*512 bf16
  u16* qbuf  = (u16*)(ws + 2097152);                     // 16 MiB
  u16* kbuf  = (u16*)(ws + 2097152 + 16777216);          // 16 MiB
  u16* vtbuf = (u16*)(ws + 2097152 + 2 * 16777216);      // 16 MiB
  u16* obuf  = (u16*)(ws + 2097152 + 3 * 16777216);      // 16 MiB
  u16* xb    = obuf;  // xb consumed by qkv_gemm before attn writes obuf

  xcast<<<4096, 256, 0, stream>>>(x, xb);
  transpose_all<<<dim3(64, 4), 256, 0, stream>>>(wq, wk, wv, wo, wT, woT);
  qkv_gemm<<<dim3(128, 6), 512, 0, stream>>>(xb, wT, qbuf, kbuf, vtbuf);
  attn<<<512, 512, 0, stream>>>(qbuf, kbuf, vtbuf, rel_row, rel_col, obuf);
  out_gemm<<<dim3(128, 2), 512, 0, stream>>>(obuf, woT, out);
}